// Round 5
// baseline (3866.491 us; speedup 1.0000x reference)
//
#include <hip/hip_runtime.h>
#include <math.h>

#define HDIM 1024
#define BDIM 64
#define TDIM 512
#define KIN  128
#define NBLK 256
#define NTHR 512            // 8 waves
#define FRAME (HDIM * BDIM) // halfs per ring frame (both bg subframes)
#define SUBF  (HDIM * 32)   // halfs per 32-batch subframe
#define D1    8             // h1 ring depth (lag window between layers)

typedef _Float16 f16;
typedef __attribute__((ext_vector_type(2))) _Float16 f16x2;
typedef __attribute__((ext_vector_type(8))) _Float16 f16x8;
typedef __attribute__((ext_vector_type(4))) float f32x4;
typedef __attribute__((ext_vector_type(4))) unsigned u32x4;

#define MFMA16(a, b, c) __builtin_amdgcn_mfma_f32_16x16x32_f16((a), (b), (c), 0, 0, 0)

__device__ __forceinline__ float sigm(float x) { return 1.0f / (1.0f + expf(-x)); }

// ---------------------------------------------------------------------------
// r13: LAYER-SPLIT STREAMS. Blocks 0-127 = layer1, 128-255 = layer2.
// r12's post-mortem: halving ring traffic left dur flat -> we are on a
// ~14.2kcy/step latency floor (7 barriers + 2 vmcnt waits + 2 publishes + 2
// polls, serial legs for both layers). This rewrite makes each layer its own
// 128-block stream (64 cg x 16 cols, 2 bg x 32 batches) with a single-phase
// body: poll -> load -> MFMA -> 1 LDS reduce -> activate -> publish
// (3 barriers, 1 vmcnt, 1 publish). Streams couple via an 8-deep h1 ring:
// layer1 runs ahead up to D1 steps; global period = max(leg1, leg2), not sum.
// Subframe layout (halfs): idx(k, b32) = (k>>3)*256 + b32*8 + (k&7).
// All ring I/O sc0sc1 (L3 coherence point; r11 showed cached+inv is 6x worse).
// ---------------------------------------------------------------------------
__device__ __forceinline__ f16x8 ld_cg(const f16* p) {
    f16x8 r;
    asm volatile("global_load_dwordx4 %0, %1, off sc0 sc1"
                 : "=v"(r) : "v"(p) : "memory");
    return r;
}
__device__ __forceinline__ void st_cg16(f16* p, u32x4 v) {
    asm volatile("global_store_dwordx4 %0, %1, off sc0 sc1"
                 :: "v"(p), "v"(v) : "memory");
}
// waitcnt + sched_barrier: keeps reg-only MFMAs from hoisting above the wait
#define VM_WAIT_ALL()                                                    \
    do {                                                                 \
        asm volatile("s_waitcnt vmcnt(0)" ::: "memory");                 \
        __builtin_amdgcn_sched_barrier(0);                               \
    } while (0)

__device__ __forceinline__ void tag_pub(unsigned* tag, unsigned v) {
    asm volatile("global_store_dword %0, %1, off sc0 sc1"
                 :: "v"(tag), "v"(v) : "memory");
}
// Poll a 128-dword tag segment: dwords [0..63] = layer1 cg tags (target tA),
// [64..127] = layer2 cg tags (target tB). One dwordx4 per lane, 2x duplicated.
__device__ __forceinline__ void poll2(const unsigned* seg, int lane,
                                      unsigned tA, unsigned tB) {
    const int li = lane & 31;
    const unsigned* p = seg + li * 4;
    const unsigned tgt = (li < 16) ? tA : tB;
    for (;;) {
        u32x4 t;
        asm volatile("global_load_dwordx4 %0, %1, off sc0 sc1\n\t"
                     "s_waitcnt vmcnt(0)"
                     : "=v"(t) : "v"(p) : "memory");
        bool ok = (t.x >= tgt) && (t.y >= tgt) && (t.z >= tgt) && (t.w >= tgt);
        if (__all(ok)) break;
        __builtin_amdgcn_s_sleep(1);
    }
}

// ---------------------------------------------------------------------------
__global__ void cvt_w(const float* __restrict__ src, f16* __restrict__ dst, int n2) {
    int i = blockIdx.x * blockDim.x + threadIdx.x;
    if (i < n2) {
        float2 a = ((const float2*)src)[i];
        f16x2 o = {(f16)a.x, (f16)a.y};
        ((f16x2*)dst)[i] = o;
    }
}

// x[b][t][k] fp32 -> xP[t][b][k] fp16
__global__ void cvt_x(const float* __restrict__ x, f16* __restrict__ xP) {
    int P = blockIdx.x * blockDim.x + threadIdx.x;    // pair index
    if (P >= TDIM * BDIM * (KIN / 2)) return;
    int kp = P & 63;
    int b  = (P >> 6) & 63;
    int t  = P >> 12;
    float2 v = ((const float2*)x)[((size_t)b * TDIM + t) * (KIN / 2) + kp];
    f16x2 o = {(f16)v.x, (f16)v.y};
    ((f16x2*)xP)[((size_t)t * BDIM + b) * (KIN / 2) + kp] = o;
}

// ---------------------------------------------------------------------------
// Roles: bid<128 -> layer1 block; bid>=128 -> layer2 block.
// Within role: idx = bid&127; cg = idx&63 (16 cols at i0=cg*16), bg = idx>>6
// (32 batches at b0=bg*32). 8 waves; K-split 8.
//   L1: Whh0 K=1024 -> 4 j-chunks/wave; x K=128 on waves 0-3 (chunk w).
//   L2: combined K=2048: waves 0-3 = Wih1 slices (A from ring1 h1^{(t)}),
//       waves 4-7 = Whh1 slices (A from ring2 h2^{(t-1)}). 8 j-chunks/wave.
// Reduce: every wave writes 8 tile-partials; one barrier; all 8 waves are
// owners (lane -> col cO=w*2+(lane>>5), batch b32O=lane&31) summing 8
// partials + bias -> gates -> c/h update -> hbuf; barrier; wave1 publishes
// 1KB contiguous + drain + tag.
// Tags: seg[bg*128]: [cg]=L1 progress, [64+cg]=L2 progress (value=step+2).
//   L1 step s: needs tagL1>=s+1 (h1^{(s-1)}), and s>=D1: tagL2>=s-D1+2
//              (ring1 slot reuse window).
//   L2 step t: needs tagL1>=t+2 (h1^{(t)}), tagL2>=t+1 (h2^{(t-1)}).
// ---------------------------------------------------------------------------
__global__ void __launch_bounds__(NTHR) lstm_fused(
    const f16* __restrict__ xP,
    const f16* __restrict__ Wc0, const f16* __restrict__ Wh0,
    const float* __restrict__ bih0, const float* __restrict__ bhh0,
    const f16* __restrict__ Wc1, const f16* __restrict__ Wh1,
    const float* __restrict__ bih1, const float* __restrict__ bhh1,
    f16* ring1, f16* ring2, unsigned* tags, unsigned* tagUnused) {

    __shared__ float red[64 * 324 + 16];           // ~83 KB partials
    __shared__ __align__(16) f16 hbuf[32 * 16];    // [(c>>3)*32+b]*8+(c&7)

    const int tid  = threadIdx.x;
    const int lane = tid & 63;
    const int w    = __builtin_amdgcn_readfirstlane(tid >> 6);   // 0..7
    const int bid  = (int)blockIdx.x;
    const int role = __builtin_amdgcn_readfirstlane(bid >> 7);   // 0=L1 1=L2
    const int idx  = bid & 127;
    const int cg   = __builtin_amdgcn_readfirstlane(idx & 63);
    const int bg   = __builtin_amdgcn_readfirstlane(idx >> 6);
    const int i0   = cg * 16;
    const int b0   = bg * 32;

    const int n    = lane & 15;
    const int quad = lane >> 4;
    const int am   = lane & 15;
    const int kq   = quad * 8;

    // weight rows for the 4 N-tiles
    int wr[4];
    #pragma unroll
    for (int nt = 0; nt < 4; ++nt)
        wr[nt] = i0 + nt * 4 + (n >> 2) + (n & 3) * HDIM;

    // owner decomposition (every wave owns 2 cols x 32 batches)
    const int cO   = w * 2 + (lane >> 5);
    const int b32O = lane & 31;
    const int mtO  = (lane >> 4) & 1;
    const int qmO  = lane & 15;
    const int ntO  = cO >> 2;
    const int cit  = cO & 3;       // col within tile

    unsigned* seg   = tags + bg * 128;
    unsigned* mytag = seg + (role ? 64 + cg : cg);

    float bias[4];
    float cc = 0.f;                // c1 or c2 state for owned (col,batch)
    {
        const float* bi = role ? bih1 : bih0;
        const float* bh = role ? bhh1 : bhh0;
        const int i = i0 + cO;
        #pragma unroll
        for (int g = 0; g < 4; ++g)
            bias[g] = bi[i + g * HDIM] + bh[i + g * HDIM];
    }

    if (role == 0) {
        // ---- layer 1 ----
        f16x8 B1h[4][4];
        f16x8 B1x[4];
        #pragma unroll
        for (int j = 0; j < 4; ++j) {
            const int ks = (w * 4 + j) * 32 + kq;
            #pragma unroll
            for (int nt = 0; nt < 4; ++nt)
                B1h[j][nt] = *(const f16x8*)(Wh0 + (size_t)wr[nt] * HDIM + ks);
        }
        if (w < 4)
            #pragma unroll
            for (int nt = 0; nt < 4; ++nt)
                B1x[nt] = *(const f16x8*)(Wc0 + (size_t)wr[nt] * KIN + w * 32 + kq);

        // init: zero own 1KB of ring1 slot D1-1 (h1^{(-1)}), tag=1
        if (w == 2) {
            u32x4 z = {0u, 0u, 0u, 0u};
            st_cg16(ring1 + (size_t)(D1 - 1) * FRAME + bg * SUBF + cg * 512 + lane * 8, z);
            VM_WAIT_ALL();
            if (lane == 0) tag_pub(mytag, 1u);
        }

        for (int s = 0; s < TDIM; ++s) {
            const f16* rp = ring1 + (size_t)((s + D1 - 1) & (D1 - 1)) * FRAME + bg * SUBF;
            if (w == 0)
                poll2(seg, lane, (unsigned)(s + 1),
                      (unsigned)((s >= D1) ? (s - D1 + 2) : 0));
            __syncthreads();   // S1

            f16x8 A[4][2];
            #pragma unroll
            for (int j = 0; j < 4; ++j) {
                const int oct = (w * 4 + j) * 4 + quad;
                #pragma unroll
                for (int mt = 0; mt < 2; ++mt)
                    A[j][mt] = ld_cg(rp + oct * 256 + (mt * 16 + am) * 8);
            }
            f16x8 ax[2];
            if (w < 4) {
                const f16* xb = xP + (size_t)s * BDIM * KIN;
                #pragma unroll
                for (int mt = 0; mt < 2; ++mt)
                    ax[mt] = *(const f16x8*)(xb + (size_t)(b0 + mt * 16 + am) * KIN + w * 32 + kq);
            }
            VM_WAIT_ALL();

            f32x4 acc[2][4];
            #pragma unroll
            for (int mt = 0; mt < 2; ++mt)
                #pragma unroll
                for (int nt = 0; nt < 4; ++nt)
                    acc[mt][nt] = (f32x4){0.f, 0.f, 0.f, 0.f};
            #pragma unroll
            for (int j = 0; j < 4; ++j)
                #pragma unroll
                for (int nt = 0; nt < 4; ++nt)
                    #pragma unroll
                    for (int mt = 0; mt < 2; ++mt)
                        acc[mt][nt] = MFMA16(A[j][mt], B1h[j][nt], acc[mt][nt]);
            if (w < 4)
                #pragma unroll
                for (int nt = 0; nt < 4; ++nt)
                    #pragma unroll
                    for (int mt = 0; mt < 2; ++mt)
                        acc[mt][nt] = MFMA16(ax[mt], B1x[nt], acc[mt][nt]);

            #pragma unroll
            for (int mt = 0; mt < 2; ++mt)
                #pragma unroll
                for (int nt = 0; nt < 4; ++nt)
                    *(f32x4*)&red[(w * 8 + mt * 4 + nt) * 324 + n * 20 + quad * 4] = acc[mt][nt];
            __syncthreads();   // S2

            {
                float g4[4];
                #pragma unroll
                for (int g = 0; g < 4; ++g) {
                    float sum = bias[g];
                    #pragma unroll
                    for (int p = 0; p < 8; ++p)
                        sum += red[(p * 8 + mtO * 4 + ntO) * 324 + (cit * 4 + g) * 20 + qmO];
                    g4[g] = sum;
                }
                float ig = sigm(g4[0]), fg = sigm(g4[1]);
                float gg = tanhf(g4[2]), og = sigm(g4[3]);
                cc = fg * cc + ig * gg;
                hbuf[((cO >> 3) * 32 + b32O) * 8 + (cO & 7)] = (f16)(og * tanhf(cc));
            }
            __syncthreads();   // S3

            if (w == 1) {
                u32x4 v = *(const u32x4*)&hbuf[lane * 8];
                st_cg16(ring1 + (size_t)(s & (D1 - 1)) * FRAME + bg * SUBF + cg * 512 + lane * 8, v);
                VM_WAIT_ALL();
                if (lane == 0) tag_pub(mytag, (unsigned)(s + 2));
            }
        }
    } else {
        // ---- layer 2 ----
        f16x8 B2[8][4];    // waves 0-3: Wih1 slices; waves 4-7: Whh1 slices
        {
            const f16* mat = (w < 4) ? Wc1 : Wh1;
            #pragma unroll
            for (int j = 0; j < 8; ++j) {
                const int ks = ((w & 3) * 8 + j) * 32 + kq;
                #pragma unroll
                for (int nt = 0; nt < 4; ++nt)
                    B2[j][nt] = *(const f16x8*)(mat + (size_t)wr[nt] * HDIM + ks);
            }
        }

        // init: zero own 1KB of ring2 frame 1 (h2^{(-1)}), tag=1
        if (w == 2) {
            u32x4 z = {0u, 0u, 0u, 0u};
            st_cg16(ring2 + (size_t)FRAME + bg * SUBF + cg * 512 + lane * 8, z);
            VM_WAIT_ALL();
            if (lane == 0) tag_pub(mytag, 1u);
        }

        for (int t = 0; t < TDIM; ++t) {
            const f16* r1p = ring1 + (size_t)(t & (D1 - 1)) * FRAME + bg * SUBF;   // h1^{(t)}
            const f16* r2p = ring2 + (size_t)((t + 1) & 1) * FRAME + bg * SUBF;    // h2^{(t-1)}
            if (w == 0)
                poll2(seg, lane, (unsigned)(t + 2), (unsigned)(t + 1));
            __syncthreads();   // S1

            const f16* base = (w < 4) ? r1p : r2p;
            f16x8 A[8][2];
            #pragma unroll
            for (int j = 0; j < 8; ++j) {
                const int oct = ((w & 3) * 8 + j) * 4 + quad;
                #pragma unroll
                for (int mt = 0; mt < 2; ++mt)
                    A[j][mt] = ld_cg(base + oct * 256 + (mt * 16 + am) * 8);
            }
            VM_WAIT_ALL();

            f32x4 acc[2][4];
            #pragma unroll
            for (int mt = 0; mt < 2; ++mt)
                #pragma unroll
                for (int nt = 0; nt < 4; ++nt)
                    acc[mt][nt] = (f32x4){0.f, 0.f, 0.f, 0.f};
            #pragma unroll
            for (int j = 0; j < 8; ++j)
                #pragma unroll
                for (int nt = 0; nt < 4; ++nt)
                    #pragma unroll
                    for (int mt = 0; mt < 2; ++mt)
                        acc[mt][nt] = MFMA16(A[j][mt], B2[j][nt], acc[mt][nt]);

            #pragma unroll
            for (int mt = 0; mt < 2; ++mt)
                #pragma unroll
                for (int nt = 0; nt < 4; ++nt)
                    *(f32x4*)&red[(w * 8 + mt * 4 + nt) * 324 + n * 20 + quad * 4] = acc[mt][nt];
            __syncthreads();   // S2

            {
                float g4[4];
                #pragma unroll
                for (int g = 0; g < 4; ++g) {
                    float sum = bias[g];
                    #pragma unroll
                    for (int p = 0; p < 8; ++p)
                        sum += red[(p * 8 + mtO * 4 + ntO) * 324 + (cit * 4 + g) * 20 + qmO];
                    g4[g] = sum;
                }
                float ig = sigm(g4[0]), fg = sigm(g4[1]);
                float gg = tanhf(g4[2]), og = sigm(g4[3]);
                cc = fg * cc + ig * gg;
                hbuf[((cO >> 3) * 32 + b32O) * 8 + (cO & 7)] = (f16)(og * tanhf(cc));
            }
            __syncthreads();   // S3

            if (w == 1) {
                u32x4 v = *(const u32x4*)&hbuf[lane * 8];
                st_cg16(ring2 + (size_t)(t & 1) * FRAME + bg * SUBF + cg * 512 + lane * 8, v);
                VM_WAIT_ALL();
                if (lane == 0) tag_pub(mytag, (unsigned)(t + 2));
            }
        }
    }
    // final h2^{(511)} is in ring2 frame 1
}

// ---------------------------------------------------------------------------
// out[b] = dot(h2[b, :], fc_w) + fc_b.  h2 in subframe/octet layout:
//   idx(k, b) = (b>>5)*SUBF + (k>>3)*256 + (b&31)*8 + (k&7)
// ---------------------------------------------------------------------------
__global__ void fc_kernel(const f16* __restrict__ h2f,
                          const float* __restrict__ fcw,
                          const float* __restrict__ fcb,
                          float* __restrict__ out) {
    __shared__ float red[256];
    const int tid = threadIdx.x;
    const int b = tid >> 2, q = tid & 3;
    const int base = (b >> 5) * SUBF + (b & 31) * 8;
    float s = 0.f;
    for (int oct = q * 32; oct < (q + 1) * 32; ++oct) {
        f16x8 v = *(const f16x8*)(h2f + base + oct * 256);
        #pragma unroll
        for (int j = 0; j < 8; ++j)
            s = fmaf((float)v[j], fcw[oct * 8 + j], s);
    }
    red[tid] = s;
    __syncthreads();
    if (q == 0)
        out[b] = red[tid] + red[tid + 1] + red[tid + 2] + red[tid + 3] + fcb[0];
}

// ---------------------------------------------------------------------------
extern "C" void kernel_launch(void* const* d_in, const int* in_sizes, int n_in,
                              void* d_out, int out_size, void* d_ws, size_t ws_size,
                              hipStream_t stream) {
    const float* x    = (const float*)d_in[0];
    const float* Wih0 = (const float*)d_in[1];
    const float* Whh0 = (const float*)d_in[2];
    const float* bih0 = (const float*)d_in[3];
    const float* bhh0 = (const float*)d_in[4];
    const float* Wih1 = (const float*)d_in[5];
    const float* Whh1 = (const float*)d_in[6];
    const float* bih1 = (const float*)d_in[7];
    const float* bhh1 = (const float*)d_in[8];
    const float* fcw  = (const float*)d_in[9];
    const float* fcb  = (const float*)d_in[10];
    float* out = (float*)d_out;

    // workspace (halfs): xP | Wc0 | Wh0 | Wc1 | Wh1 | ring1(D1) | ring2(2) | tags
    f16* xPd   = (f16*)d_ws;
    f16* Wc0   = xPd + (size_t)TDIM * BDIM * KIN;
    f16* Wh0   = Wc0 + (size_t)4 * HDIM * KIN;
    f16* Wc1   = Wh0 + (size_t)4 * HDIM * HDIM;
    f16* Wh1   = Wc1 + (size_t)4 * HDIM * HDIM;
    f16* ring1 = Wh1 + (size_t)4 * HDIM * HDIM;
    f16* ring2 = ring1 + (size_t)D1 * FRAME;
    unsigned* tags = (unsigned*)(ring2 + 2 * FRAME);

    hipMemsetAsync(tags, 0, 4096, stream);
    {
        int n2 = 4 * HDIM * KIN / 2;
        cvt_w<<<dim3((n2 + 255) / 256), dim3(256), 0, stream>>>(Wih0, Wc0, n2);
        n2 = 4 * HDIM * HDIM / 2;
        cvt_w<<<dim3((n2 + 255) / 256), dim3(256), 0, stream>>>(Whh0, Wh0, n2);
        cvt_w<<<dim3((n2 + 255) / 256), dim3(256), 0, stream>>>(Whh1, Wh1, n2);
        cvt_w<<<dim3((n2 + 255) / 256), dim3(256), 0, stream>>>(Wih1, Wc1, n2);
    }
    {
        int np = TDIM * BDIM * (KIN / 2);
        cvt_x<<<dim3((np + 255) / 256), dim3(256), 0, stream>>>(x, xPd);
    }

    void* args[13];
    args[0]  = (void*)&xPd;
    args[1]  = (void*)&Wc0;
    args[2]  = (void*)&Wh0;
    args[3]  = (void*)&bih0;
    args[4]  = (void*)&bhh0;
    args[5]  = (void*)&Wc1;
    args[6]  = (void*)&Wh1;
    args[7]  = (void*)&bih1;
    args[8]  = (void*)&bhh1;
    args[9]  = (void*)&ring1;
    args[10] = (void*)&ring2;
    args[11] = (void*)&tags;
    args[12] = (void*)&tags;   // unused slot (kept for arg-count compat)
    hipLaunchCooperativeKernel(reinterpret_cast<void*>(lstm_fused), dim3(NBLK), dim3(NTHR),
                               args, 0, stream);

    fc_kernel<<<dim3(1), dim3(256), 0, stream>>>(ring2 + FRAME, fcw, fcb, out);
}